// Round 10
// baseline (234.555 us; speedup 1.0000x reference)
//
#include <hip/hip_runtime.h>
#include <hip/hip_bf16.h>
#include <math.h>

#define B_  4
#define S_  2048
#define D_  256
#define H_  8
#define HD_ 32
// 1/sqrt(32) * log2(e): folded into Q so softmax is a bare exp2
#define QSCALE 0.25504175929589786f

typedef short  bf16x8 __attribute__((ext_vector_type(8)));
typedef float  f32x4  __attribute__((ext_vector_type(4)));
typedef float  f32x16 __attribute__((ext_vector_type(16)));
typedef unsigned short ushort_t;
typedef unsigned int   uint_t;

__device__ __forceinline__ ushort_t f2b(float f) {
    union { float f; unsigned u; } v; v.f = f;
    unsigned r = (v.u + 0x7FFFu + ((v.u >> 16) & 1u)) >> 16;
    return (ushort_t)r;
}
__device__ __forceinline__ float b2f(ushort_t s) {
    return __uint_as_float((uint_t)s << 16);
}
__device__ __forceinline__ f32x16 zero16() {
    f32x16 z;
#pragma unroll
    for (int i = 0; i < 16; ++i) z[i] = 0.f;
    return z;
}
__device__ __forceinline__ float wave_allsum(float v) {
#pragma unroll
    for (int o = 32; o > 0; o >>= 1) v += __shfl_xor(v, o, 64);
    return v;
}

// ---------------- prep: weight cvt+frag-reorder | barrier-free layernorm ----------------
#define WQ_SZ 196608   // 768*256
#define WS_SZ 65536    // 256*256
#define NB_WC  2560    // (WQ_SZ+7*WS_SZ)/256
#define NB_LN4 2048    // 8192 rows, 4 rows per block (wave-per-row, no barriers)
__global__ __launch_bounds__(256)
void prep_kernel(const float* __restrict__ w0, const float* __restrict__ w1,
                 const float* __restrict__ w2, const float* __restrict__ w3,
                 const float* __restrict__ w4, const float* __restrict__ w5,
                 const float* __restrict__ w6, const float* __restrict__ w7,
                 ushort_t* __restrict__ wout,
                 const float* __restrict__ x, const float* __restrict__ g,
                 const float* __restrict__ bb, ushort_t* __restrict__ xn_b) {
    int blk = blockIdx.x, tid = threadIdx.x;
    if (blk < NB_WC) {
        int idx = blk * 256 + tid;
        const float* src; int o;
        if (idx < WQ_SZ) { src = w0; o = idx; }
        else {
            int j = idx - WQ_SZ, seg = j >> 16; o = j & (WS_SZ - 1);
            src = (seg == 0) ? w1 : (seg == 1) ? w2 : (seg == 2) ? w3 :
                  (seg == 3) ? w4 : (seg == 4) ? w5 : (seg == 5) ? w6 : w7;
        }
        int j  = o & 7;
        int l  = (o >> 3) & 15;
        int qd = (o >> 7) & 3;
        int ks = (o >> 9) & 7;
        int ct = o >> 12;
        wout[idx] = f2b(src[(ct * 16 + l) * 256 + ks * 32 + qd * 8 + j]);
    } else {
        // layernorm: wave-per-row, 4 f32/lane, shfl_xor all-reduce, zero barriers
        int wave = tid >> 6, lane = tid & 63;
        int row = (blk - NB_WC) * 4 + wave;
        int col = lane * 4;
        float4 t = *(const float4*)(x + (size_t)row * 256 + col);
        float s = wave_allsum(t.x + t.y + t.z + t.w);
        float mu = s * (1.0f / D_);
        float d0 = t.x - mu, d1 = t.y - mu, d2 = t.z - mu, d3 = t.w - mu;
        float v = wave_allsum(d0 * d0 + d1 * d1 + d2 * d2 + d3 * d3);
        float rstd = rsqrtf(v * (1.0f / D_) + 1e-5f);
        float4 gv = *(const float4*)(g + col);
        float4 bv = *(const float4*)(bb + col);
        union { ushort_t u[4]; uint2 q; } o;
        o.u[0] = f2b(d0 * rstd * gv.x + bv.x);
        o.u[1] = f2b(d1 * rstd * gv.y + bv.y);
        o.u[2] = f2b(d2 * rstd * gv.z + bv.z);
        o.u[3] = f2b(d3 * rstd * gv.w + bv.w);
        *(uint2*)(xn_b + (size_t)row * 256 + col) = o.q;
    }
}

// ---------------- QKV GEMM + V/K emission, with interleaved adj->bits blocks ----------------
// grid 9728 = 512 groups x 19 blocks: 3 gemm (1536 total) + 16 adj (8192 total) per group.
// The adj pass is HBM-bound and independent of gemm -- co-scheduling hides it entirely.
// bits layout (transposed): bits[(b*64 + word)*2048 + q].
__global__ __launch_bounds__(256)
void gemm_qkv(const ushort_t* __restrict__ A, const ushort_t* __restrict__ Wf,
              const float* __restrict__ bias, ushort_t* __restrict__ outb,
              ushort_t* __restrict__ vT, ushort_t* __restrict__ kD,
              const int* __restrict__ adj, uint_t* __restrict__ bits) {
    __shared__ ushort_t Sa[64][264];
    int tid = threadIdx.x;
    int bid = blockIdx.x;
    int grp = bid / 19, r = bid - grp * 19;
    if (r >= 3) {
        // ---- adj -> transposed bitmask ----
        int a = grp * 16 + (r - 3);              // [0, 8192): one (b,q) row
        int lane = tid & 63;
        uint_t* outp = bits + ((size_t)(a >> 11) * 64) * 2048 + (a & 2047);
#pragma unroll
        for (int gp = 0; gp < 8; ++gp) {
            size_t i = ((size_t)a * 8 + gp) * 256 + tid;
            unsigned long long m = __ballot(adj[i] != 0);
            int w = gp * 8 + ((tid & ~63) >> 5);
            if (lane == 0)  outp[(size_t)w * 2048]       = (uint_t)m;
            if (lane == 32) outp[(size_t)(w + 1) * 2048] = (uint_t)(m >> 32);
        }
        return;
    }
    int gidx = grp * 3 + r;                      // [0, 1536)
    int m0 = (gidx / 12) * 64, n0 = (gidx % 12) * 64;

    int wave = tid >> 6, lane = tid & 63, l = lane & 15, quad = lane >> 4;
    int wm = wave >> 1, wn = wave & 1;
    {
        // coalesced A staging: lane-consecutive 16B, 512B bursts per instruction
#pragma unroll
        for (int j = 0; j < 8; ++j) {
            int u = tid + j * 256;
            int row = u >> 5, c = (u & 31) * 8;
            *(uint4*)&Sa[row][c] = *(const uint4*)(A + (size_t)(m0 + row) * 256 + c);
        }
    }
    __syncthreads();

    bf16x8 af[2][8];
#pragma unroll
    for (int mt = 0; mt < 2; ++mt)
#pragma unroll
        for (int ks = 0; ks < 8; ++ks)
            af[mt][ks] = *(const bf16x8*)&Sa[wm * 32 + mt * 16 + l][ks * 32 + quad * 8];

    f32x4 acc[2][2];
#pragma unroll
    for (int i = 0; i < 2; ++i)
#pragma unroll
        for (int j = 0; j < 2; ++j) acc[i][j] = (f32x4){0.f, 0.f, 0.f, 0.f};

#pragma unroll
    for (int nt = 0; nt < 2; ++nt) {
        int ct = (n0 >> 4) + wn * 2 + nt;
        bf16x8 wfr[8];
#pragma unroll
        for (int ks = 0; ks < 8; ++ks)
            wfr[ks] = *(const bf16x8*)(Wf + (((size_t)ct * 8 + ks) * 64 + lane) * 8);
#pragma unroll
        for (int ks = 0; ks < 8; ++ks) {
            acc[0][nt] = __builtin_amdgcn_mfma_f32_16x16x32_bf16(af[0][ks], wfr[ks], acc[0][nt], 0, 0, 0);
            acc[1][nt] = __builtin_amdgcn_mfma_f32_16x16x32_bf16(af[1][ks], wfr[ks], acc[1][nt], 0, 0, 0);
        }
    }

    __syncthreads();
    ushort_t* So = &Sa[0][0];
#pragma unroll
    for (int nt = 0; nt < 2; ++nt) {
        int col = wn * 32 + nt * 16 + l;
        int gcol = n0 + col;
        float bv = bias[gcol];
        float qs = ((gcol % 96) < 32) ? QSCALE : 1.0f;
#pragma unroll
        for (int mt = 0; mt < 2; ++mt)
#pragma unroll
            for (int r2 = 0; r2 < 4; ++r2) {
                int row = wm * 32 + mt * 16 + quad * 4 + r2;
                So[row * 72 + col] = f2b((acc[mt][nt][r2] + bv) * qs);
            }
    }
    __syncthreads();
    {
        int row = tid >> 2, seg = tid & 3;
        uint4 v0 = *(uint4*)&So[row * 72 + seg * 16];
        uint4 v1 = *(uint4*)&So[row * 72 + seg * 16 + 8];
        ushort_t* op = outb + (size_t)(m0 + row) * 768 + n0 + seg * 16;
        ((uint4*)op)[0] = v0;
        ((uint4*)op)[1] = v1;
    }

    int vs = n0 % 96;

    // dense K emission: blocks with vs==0 hold K of head n0/96 at local cols 32..63;
    // vs==32 hold K of head (n0-32)/96 at local cols 0..31. Row-major [key][32] per head.
    if (vs != 64) {
        int kloc = (vs == 0) ? 32 : 0;
        int h  = (vs == 0) ? (n0 / 96) : ((n0 - 32) / 96);
        int b  = m0 >> 11;
        int s0 = m0 & (S_ - 1);
        int krow = tid >> 2, kd = (tid & 3) * 8;
        uint4 v = *(uint4*)&So[krow * 72 + kloc + kd];
        *(uint4*)&kD[((size_t)(b * 8 + h) * S_ + s0 + krow) * 32 + kd] = v;
    }

    if (vs != 0) {
        int vloc = (vs == 64) ? 0 : 32;
        int h  = (n0 + vloc) / 96;
        int b  = m0 >> 11;
        int s0 = m0 & (S_ - 1);
        ushort_t* vstage = &Sa[0][0] + 8192;
        {
            int c = tid & 31, seg = tid >> 5;
            ushort_t tmp[8];
#pragma unroll
            for (int i = 0; i < 8; ++i)
                tmp[i] = So[(seg * 8 + i) * 72 + vloc + c];
            uint_t u[4];
#pragma unroll
            for (int i = 0; i < 4; ++i)
                u[i] = (uint_t)tmp[2 * i] | ((uint_t)tmp[2 * i + 1] << 16);
            *(uint4*)&vstage[c * 72 + seg * 8] = make_uint4(u[0], u[1], u[2], u[3]);
        }
        __syncthreads();
        {
            int d = tid >> 3, tseg = tid & 7;
            uint4 v = *(uint4*)&vstage[d * 72 + tseg * 8];
            *(uint4*)&vT[((size_t)(b * 8 + h) * 32 + d) * S_ + s0 + tseg * 8] = v;
        }
    }
}

// ---------------- fully fused post-attention (frag-ordered weights), 8-wave ----------------
__global__ __launch_bounds__(512)
void fused_gate(const ushort_t* __restrict__ attn_b, const float* __restrict__ xf,
                const ushort_t* __restrict__ wfc, const ushort_t* __restrict__ wz,
                const ushort_t* __restrict__ uz, const ushort_t* __restrict__ wr,
                const ushort_t* __restrict__ ur, const ushort_t* __restrict__ wg,
                const ushort_t* __restrict__ ug, const float* __restrict__ bfc,
                const float* __restrict__ bz, float* __restrict__ out) {
    __shared__ ushort_t Sa[16][264];
    __shared__ ushort_t Sx[16][264];
    __shared__ ushort_t Sy[16][264];
    __shared__ ushort_t St[16][264];
    int tid = threadIdx.x;
    int wave = tid >> 6, lane = tid & 63, l = lane & 15, quad = lane >> 4;
    int m0 = blockIdx.x * 16;
    int colbase = wave * 32;

    {
        int row = tid >> 5, c0 = (tid & 31) * 8;
        const ushort_t* ap = attn_b + (size_t)(m0 + row) * 256 + c0;
        *(uint4*)&Sa[row][c0] = *((const uint4*)ap);
        const float4* xp = (const float4*)(xf + (size_t)(m0 + row) * 256 + c0);
        float4 f0 = xp[0], f1 = xp[1];
        union { __hip_bfloat162 h[4]; uint4 u; } p0;
        p0.h[0] = __float22bfloat162_rn(make_float2(f0.x, f0.y));
        p0.h[1] = __float22bfloat162_rn(make_float2(f0.z, f0.w));
        p0.h[2] = __float22bfloat162_rn(make_float2(f1.x, f1.y));
        p0.h[3] = __float22bfloat162_rn(make_float2(f1.z, f1.w));
        *(uint4*)&Sx[row][c0] = p0.u;
    }
    __syncthreads();

    {
        bf16x8 af[8];
#pragma unroll
        for (int ks = 0; ks < 8; ++ks)
            af[ks] = *(const bf16x8*)&Sa[l][ks * 32 + quad * 8];
        f32x4 ya[2];
#pragma unroll
        for (int nt = 0; nt < 2; ++nt) ya[nt] = (f32x4){0.f, 0.f, 0.f, 0.f};
#pragma unroll
        for (int nt = 0; nt < 2; ++nt) {
            size_t fb = ((size_t)(wave * 2 + nt) * 8) * 512 + lane * 8;
#pragma unroll
            for (int ks = 0; ks < 8; ++ks) {
                bf16x8 wfr = *(const bf16x8*)(wfc + fb + ks * 512);
                ya[nt] = __builtin_amdgcn_mfma_f32_16x16x32_bf16(af[ks], wfr, ya[nt], 0, 0, 0);
            }
        }
#pragma unroll
        for (int nt = 0; nt < 2; ++nt) {
            int col = colbase + nt * 16 + l;
            float bv = bfc[col];
#pragma unroll
            for (int r = 0; r < 4; ++r)
                Sy[quad * 4 + r][col] = f2b(fmaxf(ya[nt][r] + bv, 0.0f));
        }
    }
    __syncthreads();

    f32x4 az[2], ar[2], ag[2];
#pragma unroll
    for (int nt = 0; nt < 2; ++nt) {
        az[nt] = (f32x4){0.f, 0.f, 0.f, 0.f};
        ar[nt] = (f32x4){0.f, 0.f, 0.f, 0.f};
        ag[nt] = (f32x4){0.f, 0.f, 0.f, 0.f};
    }
#pragma unroll
    for (int nt = 0; nt < 2; ++nt) {
        size_t fb = ((size_t)(wave * 2 + nt) * 8) * 512 + lane * 8;
#pragma unroll
        for (int ks = 0; ks < 8; ++ks) {
            bf16x8 fy = *(const bf16x8*)&Sy[l][ks * 32 + quad * 8];
            bf16x8 fx = *(const bf16x8*)&Sx[l][ks * 32 + quad * 8];
            bf16x8 fz  = *(const bf16x8*)(wz + fb + ks * 512);
            bf16x8 fuz = *(const bf16x8*)(uz + fb + ks * 512);
            bf16x8 fr  = *(const bf16x8*)(wr + fb + ks * 512);
            bf16x8 fur = *(const bf16x8*)(ur + fb + ks * 512);
            bf16x8 fg  = *(const bf16x8*)(wg + fb + ks * 512);
            az[nt] = __builtin_amdgcn_mfma_f32_16x16x32_bf16(fy, fz,  az[nt], 0, 0, 0);
            az[nt] = __builtin_amdgcn_mfma_f32_16x16x32_bf16(fx, fuz, az[nt], 0, 0, 0);
            ar[nt] = __builtin_amdgcn_mfma_f32_16x16x32_bf16(fy, fr,  ar[nt], 0, 0, 0);
            ar[nt] = __builtin_amdgcn_mfma_f32_16x16x32_bf16(fx, fur, ar[nt], 0, 0, 0);
            ag[nt] = __builtin_amdgcn_mfma_f32_16x16x32_bf16(fy, fg,  ag[nt], 0, 0, 0);
        }
    }
#pragma unroll
    for (int nt = 0; nt < 2; ++nt) {
        int col = colbase + nt * 16 + l;
        float bzv = bz[col];
#pragma unroll
        for (int r = 0; r < 4; ++r) {
            int row = quad * 4 + r;
            az[nt][r] = 1.0f / (1.0f + __expf(-(az[nt][r] + bzv)));
            float rr  = 1.0f / (1.0f + __expf(-ar[nt][r]));
            St[row][col] = f2b(rr * b2f(Sx[row][col]));
        }
    }
    __syncthreads();

    f32x4 fcc[2];
#pragma unroll
    for (int nt = 0; nt < 2; ++nt) fcc[nt] = (f32x4){0.f, 0.f, 0.f, 0.f};
#pragma unroll
    for (int nt = 0; nt < 2; ++nt) {
        size_t fb = ((size_t)(wave * 2 + nt) * 8) * 512 + lane * 8;
#pragma unroll
        for (int ks = 0; ks < 8; ++ks) {
            bf16x8 ft = *(const bf16x8*)&St[l][ks * 32 + quad * 8];
            bf16x8 fu = *(const bf16x8*)(ug + fb + ks * 512);
            fcc[nt] = __builtin_amdgcn_mfma_f32_16x16x32_bf16(ft, fu, fcc[nt], 0, 0, 0);
        }
    }
#pragma unroll
    for (int nt = 0; nt < 2; ++nt) {
        int col = colbase + nt * 16 + l;
#pragma unroll
        for (int r = 0; r < 4; ++r) {
            int row = quad * 4 + r;
            float v = ag[nt][r] + fcc[nt][r];
            float e = __expf(2.0f * v);
            float h = 1.0f - 2.0f / (e + 1.0f);
            float zz = az[nt][r];
            size_t idx = (size_t)(m0 + row) * 256 + col;
            out[idx] = (1.0f - zz) * xf[idx] + zz * h;
        }
    }
}

// ---------------- MFMA flash attention: 32x32 in-register softmax, KVBLK=128, key-split ----------------
// Branchless main loop: 15 staged windows + peeled compute-only epilogue; prefetch
// indices clamped (&2047) so the tail prefetch reads valid (unused) memory.
#define ATTN_COMPUTE(CUR, A0, A1)                                                         \
    {                                                                                     \
        _Pragma("unroll")                                                                 \
        for (int kb2 = 0; kb2 < 2; ++kb2) {                                               \
            const int kb = kofs + kb2 * 32;                                               \
            bf16x8 kf1 = *(const bf16x8*)&Ks[CUR][kb + lane5][(hi ^ b3) * 8];             \
            bf16x8 kf2 = *(const bf16x8*)&Ks[CUR][kb + lane5][((2 + hi) ^ b3) * 8];       \
            f32x16 sc = zero16();                                                         \
            sc = __builtin_amdgcn_mfma_f32_32x32x16_bf16(kf1, qf1, sc, 0, 0, 0);          \
            sc = __builtin_amdgcn_mfma_f32_32x32x16_bf16(kf2, qf2, sc, 0, 0, 0);          \
            uint_t wsub = (kb2 ? (A1) : (A0)) >> hsh8;                                    \
            union { uint_t u[8]; bf16x8 v[2]; } pp;                                       \
            _Pragma("unroll")                                                             \
            for (int i = 0; i < 8; ++i) {                                                 \
                const int c = 2 * i + ((i >> 2) * 8);                                     \
                float e0 = __builtin_amdgcn_exp2f(sc[2 * i]);                             \
                float e1 = __builtin_amdgcn_exp2f(sc[2 * i + 1]);                         \
                uint_t mm0 = (uint_t)((int)(wsub << (31 - c)) >> 31);                     \
                uint_t mm1 = (uint_t)((int)(wsub << (30 - c)) >> 31);                     \
                e0 = __uint_as_float(__float_as_uint(e0) & mm0);                          \
                e1 = __uint_as_float(__float_as_uint(e1) & mm1);                          \
                union { __hip_bfloat162 b2; uint_t u; } p;                                \
                p.b2 = __float22bfloat162_rn(make_float2(e0, e1));                        \
                pp.u[i] = p.u;                                                            \
            }                                                                             \
            bf16x8 vb1 = *(const bf16x8*)&Vt[CUR][lane5][kb + hsh8];                      \
            bf16x8 vb2 = *(const bf16x8*)&Vt[CUR][lane5][kb + 16 + hsh8];                 \
            __builtin_amdgcn_s_setprio(1);                                                \
            oacc  = __builtin_amdgcn_mfma_f32_32x32x16_bf16(pp.v[0], vb1,  oacc,  0, 0, 0); \
            aones = __builtin_amdgcn_mfma_f32_32x32x16_bf16(pp.v[0], ones, aones, 0, 0, 0); \
            oacc  = __builtin_amdgcn_mfma_f32_32x32x16_bf16(pp.v[1], vb2,  oacc,  0, 0, 0); \
            aones = __builtin_amdgcn_mfma_f32_32x32x16_bf16(pp.v[1], ones, aones, 0, 0, 0); \
            __builtin_amdgcn_s_setprio(0);                                                \
        }                                                                                 \
    }

__global__ __launch_bounds__(256)
void attn_kernel(const ushort_t* __restrict__ qkvb, const ushort_t* __restrict__ kD,
                 const ushort_t* __restrict__ vT,
                 const uint_t* __restrict__ abits, ushort_t* __restrict__ attn_b) {
    __shared__ ushort_t Ks[2][128][40];
    __shared__ ushort_t Vt[2][32][136];

    int tid = threadIdx.x;
    int wave = tid >> 6, lane = tid & 63;
    int lane5 = lane & 31, hi = lane >> 5;
    int hsh8 = hi * 8;
    int pair = wave >> 1, half = wave & 1;

    // bijective XCD swizzle: XCD x serves L in [128x,128x+128) -> heads 4x..4x+3
    int lid = blockIdx.y * 32 + blockIdx.x;   // 1024 blocks
    int L   = (lid & 7) * 128 + (lid >> 3);
    int q0  = (L & 31) * 64;
    int n   = L >> 5;
    int b = n >> 3, h = n & 7;
    int bp = n & 3, hp = n >> 2;

    const ushort_t* base = qkvb + (size_t)b * S_ * 768 + h * 96;
    int qbase = pair * 32;
    int myq = q0 + qbase + lane5;
    const int kofs = half * 64;               // this wave's key offset within each window

    bf16x8 qf1 = *(const bf16x8*)(base + (size_t)myq * 768 + hsh8);
    bf16x8 qf2 = *(const bf16x8*)(base + (size_t)myq * 768 + 16 + hsh8);

    bf16x8 ones;
#pragma unroll
    for (int i = 0; i < 8; ++i) ones[i] = (short)0x3F80;

    f32x16 oacc = zero16(), aones = zero16();

    // staging assignments: 256 threads stage a full 128-key window (K: 2 threads/row x 32B;
    // V: 32 dims x 128 keys, 2 x uint4/thread). K rows stored at permuted index.
    int skey = tid >> 1, sj = tid & 1;        // K row 0..127, 32B half
    int prow = (skey & ~12) | ((skey & 4) << 1) | ((skey & 8) >> 1);
    int pxor = ((prow >> 3) & 1) << 3;
    int vd = tid >> 3, vk = (tid & 7) * 8;
    const ushort_t* vptr = vT + ((size_t)n * 32 + vd) * S_ + vk;
    const ushort_t* kpt  = kD + ((size_t)n * S_ + skey) * 32 + sj * 16;  // dense K rows
    const uint_t* tb = abits + ((size_t)b * 64) * 2048 + myq;

    // ---- prologue: stage window 0 (keys 0..127), prefetch window 1 into regs ----
    uint_t aw0 = tb[(size_t)(half * 2 + 0) * 2048];
    uint_t aw1 = tb[(size_t)(half * 2 + 1) * 2048];
    {
        uint4 ka = *(const uint4*)(kpt);
        uint4 kb_ = *(const uint4*)(kpt + 8);
        uint4 va = *(const uint4*)(vptr);
        uint4 vb_ = *(const uint4*)(vptr + 64);
        *(uint4*)&Ks[0][prow][(sj * 16 + 0) ^ pxor] = ka;
        *(uint4*)&Ks[0][prow][(sj * 16 + 8) ^ pxor] = kb_;
        *(uint4*)&Vt[0][vd][vk] = va;
        *(uint4*)&Vt[0][vd][vk + 64] = vb_;
    }
    uint4 kv0 = *(const uint4*)(kpt + (size_t)128 * 32);
    uint4 kv1 = *(const uint4*)(kpt + (size_t)128 * 32 + 8);
    uint4 vv0 = *(const uint4*)(vptr + 128);
    uint4 vv1 = *(const uint4*)(vptr + 192);
    __syncthreads();

    int b3 = (lane >> 3) & 1;   // bit3 of lane5 (LDS row read swizzle key)

    // ---- branchless main loop: windows 0..14 (each stages window w+1, prefetches w+2) ----
#pragma unroll 1
    for (int w = 0; w < 15; ++w) {
        int k0 = w * 128;
        int cur = w & 1;
        *(uint4*)&Ks[cur ^ 1][prow][(sj * 16 + 0) ^ pxor] = kv0;
        *(uint4*)&Ks[cur ^ 1][prow][(sj * 16 + 8) ^ pxor] = kv1;
        *(uint4*)&Vt[cur ^ 1][vd][vk] = vv0;
        *(uint4*)&Vt[cur ^ 1][vd][vk + 64] = vv1;
        int wn = ((k0 + 128) >> 5) + half * 2;
        uint_t awn0 = tb[(size_t)(wn + 0) * 2048];
        uint_t awn1 = tb[(size_t)(wn + 1) * 2048];
        int kpre = (k0 + 256) & (S_ - 1);       // clamp: tail prefetch reads valid, unused data
        kv0 = *(const uint4*)(kpt + (size_t)kpre * 32);
        kv1 = *(const uint4*)(kpt + (size_t)kpre * 32 + 8);
        vv0 = *(const uint4*)(vptr + kpre);
        vv1 = *(const uint4*)(vptr + kpre + 64);

        ATTN_COMPUTE(cur, aw0, aw1)

        aw0 = awn0; aw1 = awn1;
        __syncthreads();   // single barrier: this window's reads vs next window's writes
    }
    // ---- peeled final window (buf 1), compute only ----
    ATTN_COMPUTE(1, aw0, aw1)
    __syncthreads();       // all LDS reads done before reduction overwrites Ks

    // ---- cross-wave (key-half) reduction: odd waves dump, even waves merge ----
    float* red = (float*)&Ks[0][0][0];
    if (half) {
        float* dst = red + pair * 2048 + lane * 4;
#pragma unroll
        for (int j = 0; j < 4; ++j) {
            f32x4 t;
            t[0] = oacc[4 * j]; t[1] = oacc[4 * j + 1];
            t[2] = oacc[4 * j + 2]; t[3] = oacc[4 * j + 3];
            *(f32x4*)(dst + j * 256) = t;
        }
#pragma unroll
        for (int j = 0; j < 4; ++j) {
            f32x4 t;
            t[0] = aones[4 * j]; t[1] = aones[4 * j + 1];
            t[2] = aones[4 * j + 2]; t[3] = aones[4 * j + 3];
            *(f32x4*)(dst + (4 + j) * 256) = t;
        }
    }
    __syncthreads();
    if (!half) {
        const float* src = red + pair * 2048 + lane * 4;
#pragma unroll
        for (int j = 0; j < 4; ++j) {
            f32x4 t = *(const f32x4*)(src + j * 256);
            oacc[4 * j] += t[0]; oacc[4 * j + 1] += t[1];
            oacc[4 * j + 2] += t[2]; oacc[4 * j + 3] += t[3];
        }
#pragma unroll
        for (int j = 0; j < 4; ++j) {
            f32x4 t = *(const f32x4*)(src + (4 + j) * 256);
            aones[4 * j] += t[0]; aones[4 * j + 1] += t[1];
            aones[4 * j + 2] += t[2]; aones[4 * j + 3] += t[3];
        }
    }
    __syncthreads();   // all reduction reads done before Ost overwrites red[0]

    // oacc reg r = O[query (r&3)+8*(r>>2)+4*hi][dim lane5]
    ushort_t* Ost = &Ks[0][0][0];   // 64 rows x stride 40 (5120 B)
    if (!half) {
#pragma unroll
        for (int r = 0; r < 16; ++r) {
            int qr = (r & 3) + 8 * (r >> 2) + 4 * hi;
            Ost[(qbase + qr) * 40 + lane5] = f2b(oacc[r] / aones[r]);
        }
    }
    __syncthreads();
    {
        int row = tid >> 2, part = tid & 3;
        uint4 v = *(uint4*)&Ost[row * 40 + part * 8];
        *(uint4*)&attn_b[((size_t)(bp * S_ + q0 + row)) * 256 + hp * 32 + part * 8] = v;
    }
}

// ---------------- launch ----------------
extern "C" void kernel_launch(void* const* d_in, const int* in_sizes, int n_in,
                              void* d_out, int out_size, void* d_ws, size_t ws_size,
                              hipStream_t stream) {
    const float* x     = (const float*)d_in[0];
    const int*   adj   = (const int*)d_in[1];
    const float* w_qkv = (const float*)d_in[2];
    const float* b_qkv = (const float*)d_in[3];
    const float* ln_g  = (const float*)d_in[4];
    const float* ln_b  = (const float*)d_in[5];
    const float* w_fc  = (const float*)d_in[6];
    const float* b_fc  = (const float*)d_in[7];
    const float* w_z   = (const float*)d_in[8];
    const float* b_z   = (const float*)d_in[9];
    const float* u_z   = (const float*)d_in[10];
    const float* w_r   = (const float*)d_in[11];
    const float* u_r   = (const float*)d_in[12];
    const float* w_g   = (const float*)d_in[13];
    const float* u_g   = (const float*)d_in[14];
    float* out = (float*)d_out;

    const size_t TOK  = (size_t)B_ * S_;       // 8192
    const size_t TOKD = TOK * D_;              // 2,097,152
    ushort_t* xn_b   = (ushort_t*)d_ws;
    ushort_t* qkv_b  = xn_b + TOKD;            // TOK*768
    ushort_t* attn_b = qkv_b + TOK * 768;
    ushort_t* wb     = attn_b + TOKD;          // 655,360 elems (frag-ordered)
    uint_t*   bits   = (uint_t*)(wb + WQ_SZ + 7 * WS_SZ);   // 524,288 words (transposed layout)
    ushort_t* vTb    = (ushort_t*)(bits + (size_t)B_ * S_ * S_ / 32);  // 32 bh x 32 d x 2048
    ushort_t* kDb    = vTb + (size_t)32 * 32 * S_;           // 32 bh x 2048 keys x 32 d

    ushort_t* wq_b  = wb;
    ushort_t* wfc_b = wb + WQ_SZ;
    ushort_t* wz_b  = wfc_b + WS_SZ;
    ushort_t* uz_b  = wz_b + WS_SZ;
    ushort_t* wr_b  = uz_b + WS_SZ;
    ushort_t* ur_b  = wr_b + WS_SZ;
    ushort_t* wg_b  = ur_b + WS_SZ;
    ushort_t* ug_b  = wg_b + WS_SZ;

    prep_kernel<<<NB_WC + NB_LN4, 256, 0, stream>>>(
        w_qkv, w_fc, w_z, u_z, w_r, u_r, w_g, u_g, wb,
        x, ln_g, ln_b, xn_b);

    gemm_qkv<<<9728, 256, 0, stream>>>(xn_b, wq_b, b_qkv, qkv_b, vTb, kDb, adj, bits);

    attn_kernel<<<dim3(S_ / 64, B_ * H_), 256, 0, stream>>>(qkv_b, kDb, vTb, bits, attn_b);

    fused_gate<<<512, 512, 0, stream>>>(
        attn_b, x, wfc_b, wz_b, uz_b, wr_b, ur_b, wg_b, ug_b, b_fc, b_z, out);
}

// Round 11
// 207.863 us; speedup vs baseline: 1.1284x; 1.1284x over previous
//
#include <hip/hip_runtime.h>
#include <hip/hip_bf16.h>
#include <math.h>

#define B_  4
#define S_  2048
#define D_  256
#define H_  8
#define HD_ 32
// 1/sqrt(32) * log2(e): folded into Q so softmax is a bare exp2
#define QSCALE 0.25504175929589786f

typedef short  bf16x8 __attribute__((ext_vector_type(8)));
typedef float  f32x4  __attribute__((ext_vector_type(4)));
typedef float  f32x16 __attribute__((ext_vector_type(16)));
typedef unsigned short ushort_t;
typedef unsigned int   uint_t;

__device__ __forceinline__ ushort_t f2b(float f) {
    union { float f; unsigned u; } v; v.f = f;
    unsigned r = (v.u + 0x7FFFu + ((v.u >> 16) & 1u)) >> 16;
    return (ushort_t)r;
}
__device__ __forceinline__ float b2f(ushort_t s) {
    return __uint_as_float((uint_t)s << 16);
}
__device__ __forceinline__ f32x16 zero16() {
    f32x16 z;
#pragma unroll
    for (int i = 0; i < 16; ++i) z[i] = 0.f;
    return z;
}
__device__ __forceinline__ float wave_allsum(float v) {
#pragma unroll
    for (int o = 32; o > 0; o >>= 1) v += __shfl_xor(v, o, 64);
    return v;
}

// ---------------- prep: tiled weight cvt+frag-reorder | barrier-free layernorm ----------------
// WC: 160 blocks, one 16x256 ct-tile each -- coalesced f32 reads -> LDS -> coalesced
// fragment-ordered bf16x8 writes (replaces the old 8-line/wave gather).
#define WQ_SZ 196608   // 768*256
#define WS_SZ 65536    // 256*256
#define NB_WC2 160     // 655360 / 4096 elements per ct-tile
#define NB_LN4 2048    // 8192 rows, 4 rows per block (wave-per-row, no barriers)
__global__ __launch_bounds__(256)
void prep_kernel(const float* __restrict__ w0, const float* __restrict__ w1,
                 const float* __restrict__ w2, const float* __restrict__ w3,
                 const float* __restrict__ w4, const float* __restrict__ w5,
                 const float* __restrict__ w6, const float* __restrict__ w7,
                 ushort_t* __restrict__ wout,
                 const float* __restrict__ x, const float* __restrict__ g,
                 const float* __restrict__ bb, ushort_t* __restrict__ xn_b) {
    __shared__ float T[16][260];
    int blk = blockIdx.x, tid = threadIdx.x;
    if (blk < NB_WC2) {
        const float* src; int ct;
        if (blk < 48) { src = w0; ct = blk; }
        else {
            int j = blk - 48, seg = j >> 4; ct = j & 15;
            src = (seg == 0) ? w1 : (seg == 1) ? w2 : (seg == 2) ? w3 :
                  (seg == 3) ? w4 : (seg == 4) ? w5 : (seg == 5) ? w6 : w7;
        }
        // stage 16 rows x 256 cols, coalesced
#pragma unroll
        for (int p = 0; p < 4; ++p) {
            int u = p * 256 + tid;
            int row = u >> 6, col = (u & 63) * 4;
            float4 v = *(const float4*)(src + (size_t)(ct * 16 + row) * 256 + col);
            T[row][col]     = v.x; T[row][col + 1] = v.y;
            T[row][col + 2] = v.z; T[row][col + 3] = v.w;
        }
        __syncthreads();
        // write fragment order: out = blk*4096 + ks*512 + qd*128 + l*8 + j
        ushort_t* ob = wout + (size_t)blk * 4096;
#pragma unroll
        for (int p = 0; p < 2; ++p) {
            int m = p * 256 + tid;            // (ks,qd,l): l=m&15, qd=(m>>4)&3, ks=m>>6
            int l = m & 15, qd = (m >> 4) & 3, ks = m >> 6;
            const float* tp = &T[l][ks * 32 + qd * 8];
            union { ushort_t u[8]; uint4 q; } pk;
#pragma unroll
            for (int j = 0; j < 8; ++j) pk.u[j] = f2b(tp[j]);
            *(uint4*)(ob + ks * 512 + qd * 128 + l * 8) = pk.q;
        }
    } else {
        // layernorm: wave-per-row, 4 f32/lane, shfl_xor all-reduce, zero barriers
        int wave = tid >> 6, lane = tid & 63;
        int row = (blk - NB_WC2) * 4 + wave;
        int col = lane * 4;
        float4 t = *(const float4*)(x + (size_t)row * 256 + col);
        float s = wave_allsum(t.x + t.y + t.z + t.w);
        float mu = s * (1.0f / D_);
        float d0 = t.x - mu, d1 = t.y - mu, d2 = t.z - mu, d3 = t.w - mu;
        float v = wave_allsum(d0 * d0 + d1 * d1 + d2 * d2 + d3 * d3);
        float rstd = rsqrtf(v * (1.0f / D_) + 1e-5f);
        float4 gv = *(const float4*)(g + col);
        float4 bv = *(const float4*)(bb + col);
        union { ushort_t u[4]; uint2 q; } o;
        o.u[0] = f2b(d0 * rstd * gv.x + bv.x);
        o.u[1] = f2b(d1 * rstd * gv.y + bv.y);
        o.u[2] = f2b(d2 * rstd * gv.z + bv.z);
        o.u[3] = f2b(d3 * rstd * gv.w + bv.w);
        *(uint2*)(xn_b + (size_t)row * 256 + col) = o.q;
    }
}

// ---------------- QKV GEMM + V/K emission, with interleaved adj->bits blocks ----------------
// grid 9728 = 512 groups x 19 blocks: 3 gemm (1536 total) + 16 adj (8192 total) per group.
// adj blocks: 2 x int4 loads/thread (32B = 8 keys) -> 8-bit mask byte -> LDS -> 64
// native-uint word packs + stores. No ballots, no scalar loads.
// bits layout (transposed): bits[(b*64 + word)*2048 + q].
__global__ __launch_bounds__(256)
void gemm_qkv(const ushort_t* __restrict__ A, const ushort_t* __restrict__ Wf,
              const float* __restrict__ bias, ushort_t* __restrict__ outb,
              ushort_t* __restrict__ vT, ushort_t* __restrict__ kD,
              const int* __restrict__ adj, uint_t* __restrict__ bits) {
    __shared__ ushort_t Sa[64][264];
    int tid = threadIdx.x;
    int bid = blockIdx.x;
    int grp = bid / 19, r = bid - grp * 19;
    if (r >= 3) {
        // ---- adj -> transposed bitmask (vectorized) ----
        int a = grp * 16 + (r - 3);              // [0, 8192): one (b,q) row
        int b = a >> 11, q = a & 2047;
        const int4* arow = (const int4*)(adj + (size_t)a * 2048);
        int4 v0 = arow[tid * 2];
        int4 v1 = arow[tid * 2 + 1];
        unsigned byte = (unsigned)(v0.x != 0)        | ((unsigned)(v0.y != 0) << 1)
                      | ((unsigned)(v0.z != 0) << 2) | ((unsigned)(v0.w != 0) << 3)
                      | ((unsigned)(v1.x != 0) << 4) | ((unsigned)(v1.y != 0) << 5)
                      | ((unsigned)(v1.z != 0) << 6) | ((unsigned)(v1.w != 0) << 7);
        unsigned char* lb = (unsigned char*)&Sa[0][0];
        lb[tid] = (unsigned char)byte;
        __syncthreads();
        if (tid < 64) {
            uint_t w = *(const uint_t*)&lb[tid * 4];   // bit 8i+j = key 32*tid+8i+j
            bits[((size_t)b * 64 + tid) * 2048 + q] = w;
        }
        return;
    }
    int gidx = grp * 3 + r;                      // [0, 1536)
    int m0 = (gidx / 12) * 64, n0 = (gidx % 12) * 64;

    int wave = tid >> 6, lane = tid & 63, l = lane & 15, quad = lane >> 4;
    int wm = wave >> 1, wn = wave & 1;
    {
        // coalesced A staging: lane-consecutive 16B, 512B bursts per instruction
#pragma unroll
        for (int j = 0; j < 8; ++j) {
            int u = tid + j * 256;
            int row = u >> 5, c = (u & 31) * 8;
            *(uint4*)&Sa[row][c] = *(const uint4*)(A + (size_t)(m0 + row) * 256 + c);
        }
    }
    __syncthreads();

    bf16x8 af[2][8];
#pragma unroll
    for (int mt = 0; mt < 2; ++mt)
#pragma unroll
        for (int ks = 0; ks < 8; ++ks)
            af[mt][ks] = *(const bf16x8*)&Sa[wm * 32 + mt * 16 + l][ks * 32 + quad * 8];

    f32x4 acc[2][2];
#pragma unroll
    for (int i = 0; i < 2; ++i)
#pragma unroll
        for (int j = 0; j < 2; ++j) acc[i][j] = (f32x4){0.f, 0.f, 0.f, 0.f};

#pragma unroll
    for (int nt = 0; nt < 2; ++nt) {
        int ct = (n0 >> 4) + wn * 2 + nt;
        bf16x8 wfr[8];
#pragma unroll
        for (int ks = 0; ks < 8; ++ks)
            wfr[ks] = *(const bf16x8*)(Wf + (((size_t)ct * 8 + ks) * 64 + lane) * 8);
#pragma unroll
        for (int ks = 0; ks < 8; ++ks) {
            acc[0][nt] = __builtin_amdgcn_mfma_f32_16x16x32_bf16(af[0][ks], wfr[ks], acc[0][nt], 0, 0, 0);
            acc[1][nt] = __builtin_amdgcn_mfma_f32_16x16x32_bf16(af[1][ks], wfr[ks], acc[1][nt], 0, 0, 0);
        }
    }

    __syncthreads();
    ushort_t* So = &Sa[0][0];
#pragma unroll
    for (int nt = 0; nt < 2; ++nt) {
        int col = wn * 32 + nt * 16 + l;
        int gcol = n0 + col;
        float bv = bias[gcol];
        float qs = ((gcol % 96) < 32) ? QSCALE : 1.0f;
#pragma unroll
        for (int mt = 0; mt < 2; ++mt)
#pragma unroll
            for (int r2 = 0; r2 < 4; ++r2) {
                int row = wm * 32 + mt * 16 + quad * 4 + r2;
                So[row * 72 + col] = f2b((acc[mt][nt][r2] + bv) * qs);
            }
    }
    __syncthreads();
    {
        int row = tid >> 2, seg = tid & 3;
        uint4 v0 = *(uint4*)&So[row * 72 + seg * 16];
        uint4 v1 = *(uint4*)&So[row * 72 + seg * 16 + 8];
        ushort_t* op = outb + (size_t)(m0 + row) * 768 + n0 + seg * 16;
        ((uint4*)op)[0] = v0;
        ((uint4*)op)[1] = v1;
    }

    int vs = n0 % 96;

    // dense K emission: blocks with vs==0 hold K of head n0/96 at local cols 32..63;
    // vs==32 hold K of head (n0-32)/96 at local cols 0..31. Row-major [key][32] per head.
    if (vs != 64) {
        int kloc = (vs == 0) ? 32 : 0;
        int h  = (vs == 0) ? (n0 / 96) : ((n0 - 32) / 96);
        int b  = m0 >> 11;
        int s0 = m0 & (S_ - 1);
        int krow = tid >> 2, kd = (tid & 3) * 8;
        uint4 v = *(uint4*)&So[krow * 72 + kloc + kd];
        *(uint4*)&kD[((size_t)(b * 8 + h) * S_ + s0 + krow) * 32 + kd] = v;
    }

    if (vs != 0) {
        int vloc = (vs == 64) ? 0 : 32;
        int h  = (n0 + vloc) / 96;
        int b  = m0 >> 11;
        int s0 = m0 & (S_ - 1);
        ushort_t* vstage = &Sa[0][0] + 8192;
        {
            int c = tid & 31, seg = tid >> 5;
            ushort_t tmp[8];
#pragma unroll
            for (int i = 0; i < 8; ++i)
                tmp[i] = So[(seg * 8 + i) * 72 + vloc + c];
            uint_t u[4];
#pragma unroll
            for (int i = 0; i < 4; ++i)
                u[i] = (uint_t)tmp[2 * i] | ((uint_t)tmp[2 * i + 1] << 16);
            *(uint4*)&vstage[c * 72 + seg * 8] = make_uint4(u[0], u[1], u[2], u[3]);
        }
        __syncthreads();
        {
            int d = tid >> 3, tseg = tid & 7;
            uint4 v = *(uint4*)&vstage[d * 72 + tseg * 8];
            *(uint4*)&vT[((size_t)(b * 8 + h) * 32 + d) * S_ + s0 + tseg * 8] = v;
        }
    }
}

// ---------------- fully fused post-attention (frag-ordered weights), 8-wave ----------------
__global__ __launch_bounds__(512)
void fused_gate(const ushort_t* __restrict__ attn_b, const float* __restrict__ xf,
                const ushort_t* __restrict__ wfc, const ushort_t* __restrict__ wz,
                const ushort_t* __restrict__ uz, const ushort_t* __restrict__ wr,
                const ushort_t* __restrict__ ur, const ushort_t* __restrict__ wg,
                const ushort_t* __restrict__ ug, const float* __restrict__ bfc,
                const float* __restrict__ bz, float* __restrict__ out) {
    __shared__ ushort_t Sa[16][264];
    __shared__ ushort_t Sx[16][264];
    __shared__ ushort_t Sy[16][264];
    __shared__ ushort_t St[16][264];
    int tid = threadIdx.x;
    int wave = tid >> 6, lane = tid & 63, l = lane & 15, quad = lane >> 4;
    int m0 = blockIdx.x * 16;
    int colbase = wave * 32;

    {
        int row = tid >> 5, c0 = (tid & 31) * 8;
        const ushort_t* ap = attn_b + (size_t)(m0 + row) * 256 + c0;
        *(uint4*)&Sa[row][c0] = *((const uint4*)ap);
        const float4* xp = (const float4*)(xf + (size_t)(m0 + row) * 256 + c0);
        float4 f0 = xp[0], f1 = xp[1];
        union { __hip_bfloat162 h[4]; uint4 u; } p0;
        p0.h[0] = __float22bfloat162_rn(make_float2(f0.x, f0.y));
        p0.h[1] = __float22bfloat162_rn(make_float2(f0.z, f0.w));
        p0.h[2] = __float22bfloat162_rn(make_float2(f1.x, f1.y));
        p0.h[3] = __float22bfloat162_rn(make_float2(f1.z, f1.w));
        *(uint4*)&Sx[row][c0] = p0.u;
    }
    __syncthreads();

    {
        bf16x8 af[8];
#pragma unroll
        for (int ks = 0; ks < 8; ++ks)
            af[ks] = *(const bf16x8*)&Sa[l][ks * 32 + quad * 8];
        f32x4 ya[2];
#pragma unroll
        for (int nt = 0; nt < 2; ++nt) ya[nt] = (f32x4){0.f, 0.f, 0.f, 0.f};
#pragma unroll
        for (int nt = 0; nt < 2; ++nt) {
            size_t fb = ((size_t)(wave * 2 + nt) * 8) * 512 + lane * 8;
#pragma unroll
            for (int ks = 0; ks < 8; ++ks) {
                bf16x8 wfr = *(const bf16x8*)(wfc + fb + ks * 512);
                ya[nt] = __builtin_amdgcn_mfma_f32_16x16x32_bf16(af[ks], wfr, ya[nt], 0, 0, 0);
            }
        }
#pragma unroll
        for (int nt = 0; nt < 2; ++nt) {
            int col = colbase + nt * 16 + l;
            float bv = bfc[col];
#pragma unroll
            for (int r = 0; r < 4; ++r)
                Sy[quad * 4 + r][col] = f2b(fmaxf(ya[nt][r] + bv, 0.0f));
        }
    }
    __syncthreads();

    f32x4 az[2], ar[2], ag[2];
#pragma unroll
    for (int nt = 0; nt < 2; ++nt) {
        az[nt] = (f32x4){0.f, 0.f, 0.f, 0.f};
        ar[nt] = (f32x4){0.f, 0.f, 0.f, 0.f};
        ag[nt] = (f32x4){0.f, 0.f, 0.f, 0.f};
    }
#pragma unroll
    for (int nt = 0; nt < 2; ++nt) {
        size_t fb = ((size_t)(wave * 2 + nt) * 8) * 512 + lane * 8;
#pragma unroll
        for (int ks = 0; ks < 8; ++ks) {
            bf16x8 fy = *(const bf16x8*)&Sy[l][ks * 32 + quad * 8];
            bf16x8 fx = *(const bf16x8*)&Sx[l][ks * 32 + quad * 8];
            bf16x8 fz  = *(const bf16x8*)(wz + fb + ks * 512);
            bf16x8 fuz = *(const bf16x8*)(uz + fb + ks * 512);
            bf16x8 fr  = *(const bf16x8*)(wr + fb + ks * 512);
            bf16x8 fur = *(const bf16x8*)(ur + fb + ks * 512);
            bf16x8 fg  = *(const bf16x8*)(wg + fb + ks * 512);
            az[nt] = __builtin_amdgcn_mfma_f32_16x16x32_bf16(fy, fz,  az[nt], 0, 0, 0);
            az[nt] = __builtin_amdgcn_mfma_f32_16x16x32_bf16(fx, fuz, az[nt], 0, 0, 0);
            ar[nt] = __builtin_amdgcn_mfma_f32_16x16x32_bf16(fy, fr,  ar[nt], 0, 0, 0);
            ar[nt] = __builtin_amdgcn_mfma_f32_16x16x32_bf16(fx, fur, ar[nt], 0, 0, 0);
            ag[nt] = __builtin_amdgcn_mfma_f32_16x16x32_bf16(fy, fg,  ag[nt], 0, 0, 0);
        }
    }
#pragma unroll
    for (int nt = 0; nt < 2; ++nt) {
        int col = colbase + nt * 16 + l;
        float bzv = bz[col];
#pragma unroll
        for (int r = 0; r < 4; ++r) {
            int row = quad * 4 + r;
            az[nt][r] = 1.0f / (1.0f + __expf(-(az[nt][r] + bzv)));
            float rr  = 1.0f / (1.0f + __expf(-ar[nt][r]));
            St[row][col] = f2b(rr * b2f(Sx[row][col]));
        }
    }
    __syncthreads();

    f32x4 fcc[2];
#pragma unroll
    for (int nt = 0; nt < 2; ++nt) fcc[nt] = (f32x4){0.f, 0.f, 0.f, 0.f};
#pragma unroll
    for (int nt = 0; nt < 2; ++nt) {
        size_t fb = ((size_t)(wave * 2 + nt) * 8) * 512 + lane * 8;
#pragma unroll
        for (int ks = 0; ks < 8; ++ks) {
            bf16x8 ft = *(const bf16x8*)&St[l][ks * 32 + quad * 8];
            bf16x8 fu = *(const bf16x8*)(ug + fb + ks * 512);
            fcc[nt] = __builtin_amdgcn_mfma_f32_16x16x32_bf16(ft, fu, fcc[nt], 0, 0, 0);
        }
    }
#pragma unroll
    for (int nt = 0; nt < 2; ++nt) {
        int col = colbase + nt * 16 + l;
#pragma unroll
        for (int r = 0; r < 4; ++r) {
            int row = quad * 4 + r;
            float v = ag[nt][r] + fcc[nt][r];
            float e = __expf(2.0f * v);
            float h = 1.0f - 2.0f / (e + 1.0f);
            float zz = az[nt][r];
            size_t idx = (size_t)(m0 + row) * 256 + col;
            out[idx] = (1.0f - zz) * xf[idx] + zz * h;
        }
    }
}

// ---------------- MFMA flash attention: 32x32 in-register softmax, KVBLK=128, key-split ----------------
// Branchless main loop: 15 staged windows + peeled compute-only epilogue; prefetch
// indices clamped (&2047) so the tail prefetch reads valid (unused) memory.
#define ATTN_COMPUTE(CUR, A0, A1)                                                         \
    {                                                                                     \
        _Pragma("unroll")                                                                 \
        for (int kb2 = 0; kb2 < 2; ++kb2) {                                               \
            const int kb = kofs + kb2 * 32;                                               \
            bf16x8 kf1 = *(const bf16x8*)&Ks[CUR][kb + lane5][(hi ^ b3) * 8];             \
            bf16x8 kf2 = *(const bf16x8*)&Ks[CUR][kb + lane5][((2 + hi) ^ b3) * 8];       \
            f32x16 sc = zero16();                                                         \
            sc = __builtin_amdgcn_mfma_f32_32x32x16_bf16(kf1, qf1, sc, 0, 0, 0);          \
            sc = __builtin_amdgcn_mfma_f32_32x32x16_bf16(kf2, qf2, sc, 0, 0, 0);          \
            uint_t wsub = (kb2 ? (A1) : (A0)) >> hsh8;                                    \
            union { uint_t u[8]; bf16x8 v[2]; } pp;                                       \
            _Pragma("unroll")                                                             \
            for (int i = 0; i < 8; ++i) {                                                 \
                const int c = 2 * i + ((i >> 2) * 8);                                     \
                float e0 = __builtin_amdgcn_exp2f(sc[2 * i]);                             \
                float e1 = __builtin_amdgcn_exp2f(sc[2 * i + 1]);                         \
                uint_t mm0 = (uint_t)((int)(wsub << (31 - c)) >> 31);                     \
                uint_t mm1 = (uint_t)((int)(wsub << (30 - c)) >> 31);                     \
                e0 = __uint_as_float(__float_as_uint(e0) & mm0);                          \
                e1 = __uint_as_float(__float_as_uint(e1) & mm1);                          \
                union { __hip_bfloat162 b2; uint_t u; } p;                                \
                p.b2 = __float22bfloat162_rn(make_float2(e0, e1));                        \
                pp.u[i] = p.u;                                                            \
            }                                                                             \
            bf16x8 vb1 = *(const bf16x8*)&Vt[CUR][lane5][kb + hsh8];                      \
            bf16x8 vb2 = *(const bf16x8*)&Vt[CUR][lane5][kb + 16 + hsh8];                 \
            __builtin_amdgcn_s_setprio(1);                                                \
            oacc  = __builtin_amdgcn_mfma_f32_32x32x16_bf16(pp.v[0], vb1,  oacc,  0, 0, 0); \
            aones = __builtin_amdgcn_mfma_f32_32x32x16_bf16(pp.v[0], ones, aones, 0, 0, 0); \
            oacc  = __builtin_amdgcn_mfma_f32_32x32x16_bf16(pp.v[1], vb2,  oacc,  0, 0, 0); \
            aones = __builtin_amdgcn_mfma_f32_32x32x16_bf16(pp.v[1], ones, aones, 0, 0, 0); \
            __builtin_amdgcn_s_setprio(0);                                                \
        }                                                                                 \
    }

__global__ __launch_bounds__(256)
void attn_kernel(const ushort_t* __restrict__ qkvb, const ushort_t* __restrict__ kD,
                 const ushort_t* __restrict__ vT,
                 const uint_t* __restrict__ abits, ushort_t* __restrict__ attn_b) {
    __shared__ ushort_t Ks[2][128][40];
    __shared__ ushort_t Vt[2][32][136];

    int tid = threadIdx.x;
    int wave = tid >> 6, lane = tid & 63;
    int lane5 = lane & 31, hi = lane >> 5;
    int hsh8 = hi * 8;
    int pair = wave >> 1, half = wave & 1;

    // bijective XCD swizzle: XCD x serves L in [128x,128x+128) -> heads 4x..4x+3
    int lid = blockIdx.y * 32 + blockIdx.x;   // 1024 blocks
    int L   = (lid & 7) * 128 + (lid >> 3);
    int q0  = (L & 31) * 64;
    int n   = L >> 5;
    int b = n >> 3, h = n & 7;
    int bp = n & 3, hp = n >> 2;

    const ushort_t* base = qkvb + (size_t)b * S_ * 768 + h * 96;
    int qbase = pair * 32;
    int myq = q0 + qbase + lane5;
    const int kofs = half * 64;               // this wave's key offset within each window

    bf16x8 qf1 = *(const bf16x8*)(base + (size_t)myq * 768 + hsh8);
    bf16x8 qf2 = *(const bf16x8*)(base + (size_t)myq * 768 + 16 + hsh8);

    bf16x8 ones;
#pragma unroll
    for (int i = 0; i < 8; ++i) ones[i] = (short)0x3F80;

    f32x16 oacc = zero16(), aones = zero16();

    // staging assignments: 256 threads stage a full 128-key window (K: 2 threads/row x 32B;
    // V: 32 dims x 128 keys, 2 x uint4/thread). K rows stored at permuted index.
    int skey = tid >> 1, sj = tid & 1;        // K row 0..127, 32B half
    int prow = (skey & ~12) | ((skey & 4) << 1) | ((skey & 8) >> 1);
    int pxor = ((prow >> 3) & 1) << 3;
    int vd = tid >> 3, vk = (tid & 7) * 8;
    const ushort_t* vptr = vT + ((size_t)n * 32 + vd) * S_ + vk;
    const ushort_t* kpt  = kD + ((size_t)n * S_ + skey) * 32 + sj * 16;  // dense K rows
    const uint_t* tb = abits + ((size_t)b * 64) * 2048 + myq;

    // ---- prologue: stage window 0 (keys 0..127), prefetch window 1 into regs ----
    uint_t aw0 = tb[(size_t)(half * 2 + 0) * 2048];
    uint_t aw1 = tb[(size_t)(half * 2 + 1) * 2048];
    {
        uint4 ka = *(const uint4*)(kpt);
        uint4 kb_ = *(const uint4*)(kpt + 8);
        uint4 va = *(const uint4*)(vptr);
        uint4 vb_ = *(const uint4*)(vptr + 64);
        *(uint4*)&Ks[0][prow][(sj * 16 + 0) ^ pxor] = ka;
        *(uint4*)&Ks[0][prow][(sj * 16 + 8) ^ pxor] = kb_;
        *(uint4*)&Vt[0][vd][vk] = va;
        *(uint4*)&Vt[0][vd][vk + 64] = vb_;
    }
    uint4 kv0 = *(const uint4*)(kpt + (size_t)128 * 32);
    uint4 kv1 = *(const uint4*)(kpt + (size_t)128 * 32 + 8);
    uint4 vv0 = *(const uint4*)(vptr + 128);
    uint4 vv1 = *(const uint4*)(vptr + 192);
    __syncthreads();

    int b3 = (lane >> 3) & 1;   // bit3 of lane5 (LDS row read swizzle key)

    // ---- branchless main loop: windows 0..14 (each stages window w+1, prefetches w+2) ----
#pragma unroll 1
    for (int w = 0; w < 15; ++w) {
        int k0 = w * 128;
        int cur = w & 1;
        *(uint4*)&Ks[cur ^ 1][prow][(sj * 16 + 0) ^ pxor] = kv0;
        *(uint4*)&Ks[cur ^ 1][prow][(sj * 16 + 8) ^ pxor] = kv1;
        *(uint4*)&Vt[cur ^ 1][vd][vk] = vv0;
        *(uint4*)&Vt[cur ^ 1][vd][vk + 64] = vv1;
        int wn = ((k0 + 128) >> 5) + half * 2;
        uint_t awn0 = tb[(size_t)(wn + 0) * 2048];
        uint_t awn1 = tb[(size_t)(wn + 1) * 2048];
        int kpre = (k0 + 256) & (S_ - 1);       // clamp: tail prefetch reads valid, unused data
        kv0 = *(const uint4*)(kpt + (size_t)kpre * 32);
        kv1 = *(const uint4*)(kpt + (size_t)kpre * 32 + 8);
        vv0 = *(const uint4*)(vptr + kpre);
        vv1 = *(const uint4*)(vptr + kpre + 64);

        ATTN_COMPUTE(cur, aw0, aw1)

        aw0 = awn0; aw1 = awn1;
        __syncthreads();   // single barrier: this window's reads vs next window's writes
    }
    // ---- peeled final window (buf 1), compute only ----
    ATTN_COMPUTE(1, aw0, aw1)
    __syncthreads();       // all LDS reads done before reduction overwrites Ks

    // ---- cross-wave (key-half) reduction: odd waves dump, even waves merge ----
    float* red = (float*)&Ks[0][0][0];
    if (half) {
        float* dst = red + pair * 2048 + lane * 4;
#pragma unroll
        for (int j = 0; j < 4; ++j) {
            f32x4 t;
            t[0] = oacc[4 * j]; t[1] = oacc[4 * j + 1];
            t[2] = oacc[4 * j + 2]; t[3] = oacc[4 * j + 3];
            *(f32x4*)(dst + j * 256) = t;
        }
#pragma unroll
        for (int j = 0; j < 4; ++j) {
            f32x4 t;
            t[0] = aones[4 * j]; t[1] = aones[4 * j + 1];
            t[2] = aones[4 * j + 2]; t[3] = aones[4 * j + 3];
            *(f32x4*)(dst + (4 + j) * 256) = t;
        }
    }
    __syncthreads();
    if (!half) {
        const float* src = red + pair * 2048 + lane * 4;
#pragma unroll
        for (int j = 0; j < 4; ++j) {
            f32x4 t = *(const f32x4*)(src + j * 256);
            oacc[4 * j] += t[0]; oacc[4 * j + 1] += t[1];
            oacc[4 * j + 2] += t[2]; oacc[4 * j + 3] += t[3];
        }
#pragma unroll
        for (int j = 0; j < 4; ++j) {
            f32x4 t = *(const f32x4*)(src + (4 + j) * 256);
            aones[4 * j] += t[0]; aones[4 * j + 1] += t[1];
            aones[4 * j + 2] += t[2]; aones[4 * j + 3] += t[3];
        }
    }
    __syncthreads();   // all reduction reads done before Ost overwrites red[0]

    // oacc reg r = O[query (r&3)+8*(r>>2)+4*hi][dim lane5]
    ushort_t* Ost = &Ks[0][0][0];   // 64 rows x stride 40 (5120 B)
    if (!half) {
#pragma unroll
        for (int r = 0; r < 16; ++r) {
            int qr = (r & 3) + 8 * (r >> 2) + 4 * hi;
            Ost[(qbase + qr) * 40 + lane5] = f2b(oacc[r] / aones[r]);
        }
    }
    __syncthreads();
    {
        int row = tid >> 2, part = tid & 3;
        uint4 v = *(uint4*)&Ost[row * 40 + part * 8];
        *(uint4*)&attn_b[((size_t)(bp * S_ + q0 + row)) * 256 + hp * 32 + part * 8] = v;
    }
}

// ---------------- launch ----------------
extern "C" void kernel_launch(void* const* d_in, const int* in_sizes, int n_in,
                              void* d_out, int out_size, void* d_ws, size_t ws_size,
                              hipStream_t stream) {
    const float* x     = (const float*)d_in[0];
    const int*   adj   = (const int*)d_in[1];
    const float* w_qkv = (const float*)d_in[2];
    const float* b_qkv = (const float*)d_in[3];
    const float* ln_g  = (const float*)d_in[4];
    const float* ln_b  = (const float*)d_in[5];
    const float* w_fc  = (const float*)d_in[6];
    const float* b_fc  = (const float*)d_in[7];
    const float* w_z   = (const float*)d_in[8];
    const float* b_z   = (const float*)d_in[9];
    const float* u_z   = (const float*)d_in[10];
    const float* w_r   = (const float*)d_in[11];
    const float* u_r   = (const float*)d_in[12];
    const float* w_g   = (const float*)d_in[13];
    const float* u_g   = (const float*)d_in[14];
    float* out = (float*)d_out;

    const size_t TOK  = (size_t)B_ * S_;       // 8192
    const size_t TOKD = TOK * D_;              // 2,097,152
    ushort_t* xn_b   = (ushort_t*)d_ws;
    ushort_t* qkv_b  = xn_b + TOKD;            // TOK*768
    ushort_t* attn_b = qkv_b + TOK * 768;
    ushort_t* wb     = attn_b + TOKD;          // 655,360 elems (frag-ordered)
    uint_t*   bits   = (uint_t*)(wb + WQ_SZ + 7 * WS_SZ);   // 524,288 words (transposed layout)
    ushort_t* vTb    = (ushort_t*)(bits + (size_t)B_ * S_ * S_ / 32);  // 32 bh x 32 d x 2048
    ushort_t* kDb    = vTb + (size_t)32 * 32 * S_;           // 32 bh x 2048 keys x 32 d

    ushort_t* wq_b  = wb;
    ushort_t* wfc_b = wb + WQ_SZ;
    ushort_t* wz_b  = wfc_b + WS_SZ;
    ushort_t* uz_b  = wz_b + WS_SZ;
    ushort_t* wr_b  = uz_b + WS_SZ;
    ushort_t* ur_b  = wr_b + WS_SZ;
    ushort_t* wg_b  = ur_b + WS_SZ;
    ushort_t* ug_b  = wg_b + WS_SZ;

    prep_kernel<<<NB_WC2 + NB_LN4, 256, 0, stream>>>(
        w_qkv, w_fc, w_z, u_z, w_r, u_r, w_g, u_g, wb,
        x, ln_g, ln_b, xn_b);

    gemm_qkv<<<9728, 256, 0, stream>>>(xn_b, wq_b, b_qkv, qkv_b, vTb, kDb, adj, bits);

    attn_kernel<<<dim3(S_ / 64, B_ * H_), 256, 0, stream>>>(qkv_b, kDb, vTb, bits, attn_b);

    fused_gate<<<512, 512, 0, stream>>>(
        attn_b, x, wfc_b, wz_b, uz_b, wr_b, ur_b, wg_b, ug_b, b_fc, b_z, out);
}